// Round 2
// baseline (1787.999 us; speedup 1.0000x reference)
//
#include <hip/hip_runtime.h>
#include <math.h>

// Problem constants
#define NTOK 131072   // 64 * 2048 tokens
#define DDIM 256      // embedding dim
#define KCB  1024     // codebook size

// Output layout (fp32, concatenated in reference return order)
static constexpr size_t O_Q = 1;                          // quantized_st
static constexpr size_t O_P = 1 + (size_t)NTOK * DDIM;    // perplexity scalar
static constexpr size_t O_E = O_P + 1;                    // encodings [NTOK, KCB]
// scratch lives inside the (not yet written) encodings region; +2 floats for 16B alignment
// (f fp32 scratch removed: rescore recomputes f-rows exactly from x,W)
static constexpr size_t SCRATCH_FHI = O_E + 2;                                  // f hi bf16 (ushort)
static constexpr size_t SCRATCH_FLO = SCRATCH_FHI + (size_t)NTOK * DDIM / 2;    // f lo bf16
static constexpr size_t SCRATCH_EHI = SCRATCH_FLO + (size_t)NTOK * DDIM / 2;    // emb hi bf16
static constexpr size_t SCRATCH_ELO = SCRATCH_EHI + (size_t)KCB * DDIM / 2;     // emb lo bf16
static constexpr size_t SCRATCH_FLG = SCRATCH_ELO + (size_t)KCB * DDIM / 2;     // flagged token list (int)
// all scratch is dead before k_out overwrites the encodings region.

// ws layout (bytes)
static constexpr size_t WS_IDX   = 0;                         // NTOK * int
static constexpr size_t WS_EN    = (size_t)NTOK * 4;          // KCB * float (||e||^2)
static constexpr size_t WS_CNT   = WS_EN + (size_t)KCB * 4;   // KCB * uint (histogram)
static constexpr size_t WS_ACC   = WS_CNT + (size_t)KCB * 4;  // double (loss accumulator)
static constexpr size_t WS_FLAGN = WS_ACC + 8;                // uint (flagged-token count)

#define TS 128     // block tile (tokens) for fp32 gemm1
#define KC 32      // reduction chunk staged in LDS (gemm1)
#define LDSROW 36  // padded row stride (gemm1)

#define EPS_GAP 0.0625f   // >=30x worst-case bf16-split dot error; flags ~0.8% of tokens

typedef short bf16x8 __attribute__((ext_vector_type(8)));
typedef float f32x4  __attribute__((ext_vector_type(4)));
typedef unsigned short us4v __attribute__((ext_vector_type(4)));

__device__ __forceinline__ unsigned short f2bf(float x) {   // RNE float->bf16
    unsigned u = __float_as_uint(x);
    return (unsigned short)((u + 0x7FFFu + ((u >> 16) & 1u)) >> 16);
}
__device__ __forceinline__ float bf2f(unsigned short h) {
    return __uint_as_float(((unsigned)h) << 16);
}

// ---------------- K1: codebook squared norms + bf16 hi/lo split ----------------
__global__ __launch_bounds__(64) void k_enorm(const float* __restrict__ emb,
                                              float* __restrict__ enorm,
                                              unsigned short* __restrict__ ehi,
                                              unsigned short* __restrict__ elo) {
    int k = blockIdx.x;
    float4 v = reinterpret_cast<const float4*>(emb)[(size_t)k * 64 + threadIdx.x];
    float s = v.x * v.x + v.y * v.y + v.z * v.z + v.w * v.w;

    float xs[4] = {v.x, v.y, v.z, v.w};
    us4v hv, lv;
#pragma unroll
    for (int i = 0; i < 4; ++i) {
        unsigned short h = f2bf(xs[i]);
        hv[i] = h;
        lv[i] = f2bf(xs[i] - bf2f(h));
    }
    *reinterpret_cast<us4v*>(ehi + (size_t)k * DDIM + threadIdx.x * 4) = hv;
    *reinterpret_cast<us4v*>(elo + (size_t)k * DDIM + threadIdx.x * 4) = lv;

    for (int off = 32; off >= 1; off >>= 1) s += __shfl_down(s, off, 64);
    if (threadIdx.x == 0) enorm[k] = s;
}

// fp32 inner-product micro-kernel (gemm1). acc/bv register-promoted; is-loop
// rolled on purpose (full unroll demotes arrays to scratch).
__device__ __forceinline__ void tile_fma(const float* __restrict__ sA,
                                         const float* __restrict__ sB,
                                         int tx, int ty,
                                         float acc[8][8]) {
#pragma unroll 1
    for (int is = 0; is < 8; ++is) {
        float4 bv[8];
#pragma unroll
        for (int c = 0; c < 8; ++c)
            bv[c] = *reinterpret_cast<const float4*>(&sB[(tx + 16 * c) * LDSROW + is * 4]);
#pragma unroll
        for (int j = 0; j < 8; ++j) {
            float4 a = *reinterpret_cast<const float4*>(&sA[(ty + 16 * j) * LDSROW + is * 4]);
#pragma unroll
            for (int c = 0; c < 8; ++c)
                acc[j][c] += a.x * bv[c].x + a.y * bv[c].y + a.z * bv[c].z + a.w * bv[c].w;
        }
    }
}

// ---------------- K2: f = x @ W^T + b  (fp32) -> bf16 hi/lo only ----------------
// Register-prefetch pipeline: next K-chunk global loads issued right after the
// staging barrier so HBM latency hides under tile_fma (T14-lite).
__global__ __launch_bounds__(256, 2) void k_gemm1(const float* __restrict__ x,
                                                  const float* __restrict__ w,
                                                  const float* __restrict__ b,
                                                  unsigned short* __restrict__ fhi,
                                                  unsigned short* __restrict__ flo) {
    __shared__ float sA[TS * LDSROW];
    __shared__ float sB[TS * LDSROW];
    const int tid = threadIdx.x;
    const int tx = tid & 15, ty = tid >> 4;
    const int tb = blockIdx.x * TS;   // token base
    const int db = blockIdx.y * TS;   // output-dim base

    float acc[8][8];
#pragma unroll
    for (int j = 0; j < 8; ++j)
#pragma unroll
        for (int c = 0; c < 8; ++c) acc[j][c] = 0.f;

    const float4* x4 = reinterpret_cast<const float4*>(x);
    const float4* w4 = reinterpret_cast<const float4*>(w);

    const int pr = tid >> 3, pi = tid & 7;   // 1024 float4 per tile: 4 chunks/thread
    float4 pa[4], pb[4];
#pragma unroll
    for (int l0 = 0; l0 < 4; ++l0) {
        int row = l0 * 32 + pr;
        pa[l0] = x4[(size_t)(tb + row) * 64 + pi];
        pb[l0] = w4[(size_t)(db + row) * 64 + pi];
    }

#pragma unroll 1
    for (int kc = 0; kc < DDIM / KC; ++kc) {
        __syncthreads();                      // readers of previous tile done
#pragma unroll
        for (int l0 = 0; l0 < 4; ++l0) {
            int row = l0 * 32 + pr;
            *reinterpret_cast<float4*>(&sA[row * LDSROW + pi * 4]) = pa[l0];
            *reinterpret_cast<float4*>(&sB[row * LDSROW + pi * 4]) = pb[l0];
        }
        __syncthreads();                      // tile staged
        if (kc < DDIM / KC - 1) {
#pragma unroll
            for (int l0 = 0; l0 < 4; ++l0) {  // prefetch next chunk during compute
                int row = l0 * 32 + pr;
                pa[l0] = x4[(size_t)(tb + row) * 64 + (kc + 1) * 8 + pi];
                pb[l0] = w4[(size_t)(db + row) * 64 + (kc + 1) * 8 + pi];
            }
        }
        tile_fma(sA, sB, tx, ty, acc);
    }

    float bias[8];
#pragma unroll
    for (int c = 0; c < 8; ++c) bias[c] = b[db + tx + 16 * c];
#pragma unroll
    for (int j = 0; j < 8; ++j) {
        size_t rowo = (size_t)(tb + ty + 16 * j) * DDIM + db;
#pragma unroll
        for (int c = 0; c < 8; ++c) {
            float v = acc[j][c] + bias[c];
            int col = tx + 16 * c;
            unsigned short h = f2bf(v);
            fhi[rowo + col] = h;
            flo[rowo + col] = f2bf(v - bf2f(h));
        }
    }
}

// ---------------- K3: bf16-split MFMA distances + top-2 argmin ----------------
// d = ||e||^2 - 2*(fhi.ehi + fhi.elo + flo.ehi); exact-fp32 rescue for gap < EPS_GAP.
// 256 thr = 4 waves; 128 tokens/block. B tile (16 codes, hi+lo) staged in LDS with
// 16B-chunk XOR swizzle; next tile's global loads prefetched during MFMA compute.
__global__ __launch_bounds__(256, 2) void k_argmin_mfma(
        const unsigned short* __restrict__ fhi, const unsigned short* __restrict__ flo,
        const unsigned short* __restrict__ ehi, const unsigned short* __restrict__ elo,
        const float* __restrict__ enorm,
        int* __restrict__ idx, int* __restrict__ flaglist, unsigned* __restrict__ flagn) {
    __shared__ bf16x8 sB[1024];       // [hi:0..511][lo:512..1023]; slot = code*32 + (chunk^(code&7))
    const int tid  = threadIdx.x;
    const int lane = tid & 63;
    const int wv   = tid >> 6;
    const int row  = lane & 15;       // A row within tile == D col (code) position
    const int kg   = lane >> 4;       // k-octet group
    const int tok0 = blockIdx.x * 128 + wv * 32;

    // A fragments: 32 tokens x 256 dims (hi+lo) held in registers across whole kernel.
    bf16x8 ah[2][8], al[2][8];
#pragma unroll
    for (int m = 0; m < 2; ++m)
#pragma unroll
        for (int kk = 0; kk < 8; ++kk) {
            size_t off = (size_t)(tok0 + m * 16 + row) * DDIM + kk * 32 + kg * 8;
            ah[m][kk] = *reinterpret_cast<const bf16x8*>(fhi + off);
            al[m][kk] = *reinterpret_cast<const bf16x8*>(flo + off);
        }

    float bd1[2][4], bd2[2][4];
    int   bk1[2][4];
#pragma unroll
    for (int m = 0; m < 2; ++m)
#pragma unroll
        for (int r = 0; r < 4; ++r) { bd1[m][r] = 3.4e38f; bd2[m][r] = 3.4e38f; bk1[m][r] = 0; }

    const int sxr = row & 7;
    const int pcode = (tid >> 5) & 15, pch = tid & 31;   // staging decomposition
    const bool plo = tid >= 512 / 1;  // unused placeholder (kept simple below)

    bf16x8 st[4];
#pragma unroll
    for (int i = 0; i < 4; ++i) {     // prefetch tile 0
        int c = i * 256 + tid;
        int code = (c >> 5) & 15, ch = c & 31;
        const unsigned short* src = (c < 512) ? ehi : elo;
        st[i] = *reinterpret_cast<const bf16x8*>(src + (size_t)code * DDIM + ch * 8);
    }

#pragma unroll 1
    for (int nt = 0; nt < KCB / 16; ++nt) {
        __syncthreads();   // everyone done reading sB from previous tile
#pragma unroll
        for (int i = 0; i < 4; ++i) {
            int c = i * 256 + tid;
            int code = (c >> 5) & 15, ch = c & 31;
            sB[((c < 512) ? 0 : 512) + code * 32 + (ch ^ (code & 7))] = st[i];
        }
        __syncthreads();   // sB ready
        if (nt < KCB / 16 - 1) {
#pragma unroll
            for (int i = 0; i < 4; ++i) {   // prefetch next tile during MFMA phase
                int c = i * 256 + tid;
                int code = (c >> 5) & 15, ch = c & 31;
                const unsigned short* src = (c < 512) ? ehi : elo;
                st[i] = *reinterpret_cast<const bf16x8*>(
                    src + (size_t)((nt + 1) * 16 + code) * DDIM + ch * 8);
            }
        }

        f32x4 acc0a = {0.f, 0.f, 0.f, 0.f}, acc0b = {0.f, 0.f, 0.f, 0.f};
        f32x4 acc1a = {0.f, 0.f, 0.f, 0.f}, acc1b = {0.f, 0.f, 0.f, 0.f};
#pragma unroll
        for (int kk = 0; kk < 8; ++kk) {
            int slot = row * 32 + (((kk * 4) + kg) ^ sxr);
            bf16x8 bh = sB[slot];
            bf16x8 bl = sB[512 + slot];
            acc0a = __builtin_amdgcn_mfma_f32_16x16x32_bf16(ah[0][kk], bh, acc0a, 0, 0, 0);
            acc1a = __builtin_amdgcn_mfma_f32_16x16x32_bf16(ah[1][kk], bh, acc1a, 0, 0, 0);
            acc0b = __builtin_amdgcn_mfma_f32_16x16x32_bf16(al[0][kk], bh, acc0b, 0, 0, 0);
            acc1b = __builtin_amdgcn_mfma_f32_16x16x32_bf16(al[1][kk], bh, acc1b, 0, 0, 0);
            acc0b = __builtin_amdgcn_mfma_f32_16x16x32_bf16(ah[0][kk], bl, acc0b, 0, 0, 0);
            acc1b = __builtin_amdgcn_mfma_f32_16x16x32_bf16(ah[1][kk], bl, acc1b, 0, 0, 0);
        }

        int code = nt * 16 + row;     // D col = lane&15  [m89-verified layout]
        float en = enorm[code];
#pragma unroll
        for (int r = 0; r < 4; ++r) {
            float d0 = en - 2.f * (acc0a[r] + acc0b[r]);
            float d1 = en - 2.f * (acc1a[r] + acc1b[r]);
            if (d0 < bd1[0][r]) { bd2[0][r] = bd1[0][r]; bd1[0][r] = d0; bk1[0][r] = code; }
            else if (d0 < bd2[0][r]) bd2[0][r] = d0;
            if (d1 < bd1[1][r]) { bd2[1][r] = bd1[1][r]; bd1[1][r] = d1; bk1[1][r] = code; }
            else if (d1 < bd2[1][r]) bd2[1][r] = d1;
        }
    }

    // cross-lane top-2 merge over the 16 code columns (lanes sharing kg group)
#pragma unroll
    for (int m = 0; m < 2; ++m)
#pragma unroll
        for (int r = 0; r < 4; ++r) {
            float v1 = bd1[m][r], v2 = bd2[m][r];
            int k1 = bk1[m][r];
#pragma unroll
            for (int msk = 1; msk < 16; msk <<= 1) {
                float o1 = __shfl_xor(v1, msk, 16);
                float o2 = __shfl_xor(v2, msk, 16);
                int   ok = __shfl_xor(k1, msk, 16);
                if (o1 < v1 || (o1 == v1 && ok < k1)) { v2 = fminf(v1, o2); v1 = o1; k1 = ok; }
                else                                  { v2 = fminf(v2, o1); }
            }
            if (row == 0) {
                int t = tok0 + m * 16 + kg * 4 + r;   // D row = (lane>>4)*4 + reg
                idx[t] = k1;
                if (v2 - v1 < EPS_GAP) {              // too close for bf16 -> exact rescue
                    unsigned p = atomicAdd(flagn, 1u);
                    flaglist[p] = t;
                }
            }
        }
}

// ---------------- K3b: exact fp32 rescue (~0.8% of tokens) ----------------
// Recomputes the token's f-row from x,W in fp32 (scratchF eliminated), then exact argmin.
__global__ __launch_bounds__(256) void k_rescore(const float* __restrict__ x,
                                                 const float* __restrict__ w,
                                                 const float* __restrict__ bias,
                                                 const float* __restrict__ emb,
                                                 const float* __restrict__ enorm,
                                                 const int* __restrict__ flaglist,
                                                 const unsigned* __restrict__ flagn,
                                                 int* __restrict__ idx) {
    __shared__ float sx[DDIM];
    __shared__ float sf[DDIM];
    __shared__ float swd[4];
    __shared__ int   swk[4];
    const int tid = threadIdx.x;
    const unsigned n = *flagn;
    for (unsigned ii = blockIdx.x; ii < n; ii += gridDim.x) {
        const int t = flaglist[ii];
        __syncthreads();                               // protect sx/sf/swd reuse
        sx[tid] = x[(size_t)t * DDIM + tid];
        __syncthreads();
        // f[d] = b[d] + sum_k x[t,k] * w[d,k]   (W is L2-resident, reused across tokens)
        const float4* wr = reinterpret_cast<const float4*>(w + (size_t)tid * DDIM);
        float fd = bias[tid];
#pragma unroll 8
        for (int q = 0; q < 64; ++q) {
            float4 wv = wr[q];
            float4 xv = *reinterpret_cast<const float4*>(&sx[q * 4]);
            fd += wv.x * xv.x + wv.y * xv.y + wv.z * xv.z + wv.w * xv.w;
        }
        sf[tid] = fd;
        __syncthreads();
        float bd = 3.4e38f;
        int   bk = 0;
#pragma unroll 1
        for (int j = 0; j < 4; ++j) {
            int k = j * 256 + tid;
            const float4* er = reinterpret_cast<const float4*>(emb + (size_t)k * DDIM);
            float dot = 0.f;
#pragma unroll 8
            for (int q = 0; q < 64; ++q) {
                float4 ev = er[q];
                float4 fv = *reinterpret_cast<const float4*>(&sf[q * 4]);
                dot += ev.x * fv.x + ev.y * fv.y + ev.z * fv.z + ev.w * fv.w;
            }
            float d = enorm[k] - 2.f * dot;
            if (d < bd || (d == bd && k < bk)) { bd = d; bk = k; }
        }
        for (int m = 1; m < 64; m <<= 1) {
            float od = __shfl_xor(bd, m, 64);
            int   ok = __shfl_xor(bk, m, 64);
            if (od < bd || (od == bd && ok < bk)) { bd = od; bk = ok; }
        }
        if ((tid & 63) == 0) { swd[tid >> 6] = bd; swk[tid >> 6] = bk; }
        __syncthreads();
        if (tid == 0) {
            for (int w2 = 1; w2 < 4; ++w2)
                if (swd[w2] < bd || (swd[w2] == bd && swk[w2] < bk)) { bd = swd[w2]; bk = swk[w2]; }
            idx[t] = bk;
        }
    }
}

// ---------------- K4: fused output pass ----------------
// quantized gather + commitment-loss partial + histogram + one-hot encodings rows
// (replaces epilogue + 537MB memset + scatter; one stream of 134MB reads + 671MB writes).
__global__ __launch_bounds__(256) void k_out(const float* __restrict__ x,
                                             const float* __restrict__ emb,
                                             const int* __restrict__ idx,
                                             float* __restrict__ out,
                                             unsigned* __restrict__ counts,
                                             double* __restrict__ lossacc) {
    const int tid = threadIdx.x;
    const int tb = blockIdx.x * 64;  // 64 tokens per block
    __shared__ int   sidx[64];
    __shared__ float wsum[4];
    if (tid < 64) sidx[tid] = idx[tb + tid];
    __syncthreads();

    const float4* x4 = reinterpret_cast<const float4*>(x);
    const float4* e4 = reinterpret_cast<const float4*>(emb);
    float local = 0.f;
#pragma unroll
    for (int it = 0; it < 16; ++it) {
        int l = it * 256 + tid;
        int tok = l >> 6, q = l & 63;   // token-local float4 index
        int t = tb + tok;
        int id = sidx[tok];              // wave-uniform (64 lanes share a token)
        if (q == 0) atomicAdd(&counts[id], 1u);
        float4 xv = x4[(size_t)t * 64 + q];
        float4 ev = e4[(size_t)id * 64 + q];
        size_t o = O_Q + (size_t)t * DDIM + (size_t)q * 4;  // O_Q=1 -> scalar stores
        out[o] = ev.x; out[o + 1] = ev.y; out[o + 2] = ev.z; out[o + 3] = ev.w;
        float dx = ev.x - xv.x, dy = ev.y - xv.y, dz = ev.z - xv.z, dw = ev.w - xv.w;
        local += dx * dx + dy * dy + dz * dz + dw * dw;
    }
    for (int off = 32; off >= 1; off >>= 1) local += __shfl_down(local, off, 64);
    if ((tid & 63) == 0) wsum[tid >> 6] = local;
    __syncthreads();
    if (tid == 0)
        atomicAdd(lossacc, (double)(wsum[0] + wsum[1] + wsum[2] + wsum[3]));

    // one-hot rows: region base is only 8B-aligned (O_E = 2 mod 4 floats) -> float2 stores
#pragma unroll 1
    for (int r = 0; r < 64; ++r) {
        int id = sidx[r];
        float* rb = out + O_E + (size_t)(tb + r) * KCB;
        int hot = id >> 1, sub = id & 1;
#pragma unroll
        for (int i = 0; i < 2; ++i) {
            int q2 = i * 256 + tid;      // float2 index within the 1024-float row
            float2 v = make_float2(0.f, 0.f);
            if (q2 == hot) { if (sub) v.y = 1.f; else v.x = 1.f; }
            *reinterpret_cast<float2*>(rb + (size_t)q2 * 2) = v;
        }
    }
}

// ---------------- K6: loss + perplexity finalize ----------------
__global__ __launch_bounds__(1024) void k_final(const unsigned* __restrict__ counts,
                                                const double* __restrict__ lossacc,
                                                float* __restrict__ out) {
    int tid = threadIdx.x;
    double p = (double)counts[tid] / (double)NTOK;
    double term = p * log(p + 1e-10);
    for (int off = 32; off >= 1; off >>= 1) term += __shfl_down(term, off, 64);
    __shared__ double sw[16];
    if ((tid & 63) == 0) sw[tid >> 6] = term;
    __syncthreads();
    if (tid == 0) {
        double s = 0.0;
        for (int i = 0; i < 16; ++i) s += sw[i];
        out[O_P] = (float)exp(-s);
        out[0]   = (float)(0.25 * lossacc[0] / ((double)NTOK * (double)DDIM));
    }
}

extern "C" void kernel_launch(void* const* d_in, const int* in_sizes, int n_in,
                              void* d_out, int out_size, void* d_ws, size_t ws_size,
                              hipStream_t stream) {
    const float* x   = (const float*)d_in[0];  // [64,2048,256]
    const float* w   = (const float*)d_in[1];  // [256,256]
    const float* b   = (const float*)d_in[2];  // [256]
    const float* emb = (const float*)d_in[3];  // [1024,256]
    float* out = (float*)d_out;

    int*      idx    = (int*)((char*)d_ws + WS_IDX);
    float*    enorm  = (float*)((char*)d_ws + WS_EN);
    unsigned* counts = (unsigned*)((char*)d_ws + WS_CNT);
    double*   acc    = (double*)((char*)d_ws + WS_ACC);
    unsigned* flagn  = (unsigned*)((char*)d_ws + WS_FLAGN);

    unsigned short* fhi      = (unsigned short*)(out + SCRATCH_FHI);
    unsigned short* flo      = (unsigned short*)(out + SCRATCH_FLO);
    unsigned short* ehi      = (unsigned short*)(out + SCRATCH_EHI);
    unsigned short* elo      = (unsigned short*)(out + SCRATCH_ELO);
    int*            flaglist = (int*)(out + SCRATCH_FLG);

    // zero histogram + loss accumulator + flag count (ws is poisoned each launch)
    hipMemsetAsync((char*)d_ws + WS_CNT, 0, (size_t)KCB * 4 + 16, stream);

    k_enorm      <<<KCB,                        64,  0, stream>>>(emb, enorm, ehi, elo);
    k_gemm1      <<<dim3(NTOK / TS, DDIM / TS), 256, 0, stream>>>(x, w, b, fhi, flo);
    k_argmin_mfma<<<NTOK / 128,                 256, 0, stream>>>(fhi, flo, ehi, elo, enorm,
                                                                 idx, flaglist, flagn);
    k_rescore    <<<128,                        256, 0, stream>>>(x, w, b, emb, enorm,
                                                                 flaglist, flagn, idx);
    k_out        <<<NTOK / 64,                  256, 0, stream>>>(x, emb, idx, out, counts, acc);
    k_final      <<<1,                          1024, 0, stream>>>(counts, acc, out);
}

// Round 4
// 1481.281 us; speedup vs baseline: 1.2071x; 1.2071x over previous
//
#include <hip/hip_runtime.h>
#include <math.h>

// Problem constants
#define NTOK 131072   // 64 * 2048 tokens
#define DDIM 256      // embedding dim
#define KCB  1024     // codebook size

// Output layout (fp32, concatenated in reference return order)
static constexpr size_t O_Q = 1;                          // quantized_st
static constexpr size_t O_P = 1 + (size_t)NTOK * DDIM;    // perplexity scalar
static constexpr size_t O_E = O_P + 1;                    // encodings [NTOK, KCB]
// scratch lives inside the (not yet written) encodings region; +2 floats for 16B alignment
static constexpr size_t SCRATCH_F_OFF = O_E + 2;                                 // f fp32 [NTOK][DDIM]
static constexpr size_t SCRATCH_FHI   = SCRATCH_F_OFF + (size_t)NTOK * DDIM;     // f hi bf16 (ushort)
static constexpr size_t SCRATCH_FLO   = SCRATCH_FHI + (size_t)NTOK * DDIM / 2;   // f lo bf16
static constexpr size_t SCRATCH_EHI   = SCRATCH_FLO + (size_t)NTOK * DDIM / 2;   // emb hi bf16
static constexpr size_t SCRATCH_ELO   = SCRATCH_EHI + (size_t)KCB * DDIM / 2;    // emb lo bf16
static constexpr size_t SCRATCH_FLG   = SCRATCH_ELO + (size_t)KCB * DDIM / 2;    // flagged token list (int)
// total scratch ~68M floats < 134M encodings floats; all dead before k_out overwrites.

// ws layout (bytes)
static constexpr size_t WS_IDX   = 0;                         // NTOK * int
static constexpr size_t WS_EN    = (size_t)NTOK * 4;          // KCB * float (||e||^2)
static constexpr size_t WS_CNT   = WS_EN + (size_t)KCB * 4;   // KCB * uint (histogram)
static constexpr size_t WS_ACC   = WS_CNT + (size_t)KCB * 4;  // double (loss accumulator)
static constexpr size_t WS_FLAGN = WS_ACC + 8;                // uint (flagged-token count)

#define TS 128     // block tile (tokens) for fp32 gemm1
#define KC 32      // reduction chunk staged in LDS (gemm1)
#define LDSROW 36  // padded row stride (gemm1)

#define EPS_GAP 0.0625f   // >=30x worst-case bf16-split dot error; flags ~3% of tokens

typedef short bf16x8 __attribute__((ext_vector_type(8)));
typedef float f32x4  __attribute__((ext_vector_type(4)));
typedef unsigned short us4v __attribute__((ext_vector_type(4)));

__device__ __forceinline__ unsigned short f2bf(float x) {   // RNE float->bf16
    unsigned u = __float_as_uint(x);
    return (unsigned short)((u + 0x7FFFu + ((u >> 16) & 1u)) >> 16);
}
__device__ __forceinline__ float bf2f(unsigned short h) {
    return __uint_as_float(((unsigned)h) << 16);
}

// ---------------- K1: codebook squared norms + bf16 hi/lo split ----------------
__global__ __launch_bounds__(64) void k_enorm(const float* __restrict__ emb,
                                              float* __restrict__ enorm,
                                              unsigned short* __restrict__ ehi,
                                              unsigned short* __restrict__ elo) {
    int k = blockIdx.x;
    float4 v = reinterpret_cast<const float4*>(emb)[(size_t)k * 64 + threadIdx.x];
    float s = v.x * v.x + v.y * v.y + v.z * v.z + v.w * v.w;

    float xs[4] = {v.x, v.y, v.z, v.w};
    us4v hv, lv;
#pragma unroll
    for (int i = 0; i < 4; ++i) {
        unsigned short h = f2bf(xs[i]);
        hv[i] = h;
        lv[i] = f2bf(xs[i] - bf2f(h));
    }
    *reinterpret_cast<us4v*>(ehi + (size_t)k * DDIM + threadIdx.x * 4) = hv;
    *reinterpret_cast<us4v*>(elo + (size_t)k * DDIM + threadIdx.x * 4) = lv;

    for (int off = 32; off >= 1; off >>= 1) s += __shfl_down(s, off, 64);
    if (threadIdx.x == 0) enorm[k] = s;
}

// fp32 inner-product micro-kernel (gemm1). acc/bv register-promoted; is-loop
// rolled on purpose (full unroll demotes arrays to scratch).
__device__ __forceinline__ void tile_fma(const float* __restrict__ sA,
                                         const float* __restrict__ sB,
                                         int tx, int ty,
                                         float acc[8][8]) {
#pragma unroll 1
    for (int is = 0; is < 8; ++is) {
        float4 bv[8];
#pragma unroll
        for (int c = 0; c < 8; ++c)
            bv[c] = *reinterpret_cast<const float4*>(&sB[(tx + 16 * c) * LDSROW + is * 4]);
#pragma unroll
        for (int j = 0; j < 8; ++j) {
            float4 a = *reinterpret_cast<const float4*>(&sA[(ty + 16 * j) * LDSROW + is * 4]);
#pragma unroll
            for (int c = 0; c < 8; ++c)
                acc[j][c] += a.x * bv[c].x + a.y * bv[c].y + a.z * bv[c].z + a.w * bv[c].w;
        }
    }
}

// ---------------- K2: f = x @ W^T + b  (fp32) -> f fp32 + bf16 hi/lo ----------------
// Register-prefetch pipeline: next K-chunk global loads issued right after the
// staging barrier so HBM latency hides under tile_fma.
__global__ __launch_bounds__(256, 2) void k_gemm1(const float* __restrict__ x,
                                                  const float* __restrict__ w,
                                                  const float* __restrict__ b,
                                                  float* __restrict__ f,
                                                  unsigned short* __restrict__ fhi,
                                                  unsigned short* __restrict__ flo) {
    __shared__ float sA[TS * LDSROW];
    __shared__ float sB[TS * LDSROW];
    const int tid = threadIdx.x;
    const int tx = tid & 15, ty = tid >> 4;
    const int tb = blockIdx.x * TS;   // token base
    const int db = blockIdx.y * TS;   // output-dim base

    float acc[8][8];
#pragma unroll
    for (int j = 0; j < 8; ++j)
#pragma unroll
        for (int c = 0; c < 8; ++c) acc[j][c] = 0.f;

    const float4* x4 = reinterpret_cast<const float4*>(x);
    const float4* w4 = reinterpret_cast<const float4*>(w);

    const int pr = tid >> 3, pi = tid & 7;   // 1024 float4 per tile: 4 chunks/thread
    float4 pa[4], pb[4];
#pragma unroll
    for (int l0 = 0; l0 < 4; ++l0) {
        int row = l0 * 32 + pr;
        pa[l0] = x4[(size_t)(tb + row) * 64 + pi];
        pb[l0] = w4[(size_t)(db + row) * 64 + pi];
    }

#pragma unroll 1
    for (int kc = 0; kc < DDIM / KC; ++kc) {
        __syncthreads();                      // readers of previous tile done
#pragma unroll
        for (int l0 = 0; l0 < 4; ++l0) {
            int row = l0 * 32 + pr;
            *reinterpret_cast<float4*>(&sA[row * LDSROW + pi * 4]) = pa[l0];
            *reinterpret_cast<float4*>(&sB[row * LDSROW + pi * 4]) = pb[l0];
        }
        __syncthreads();                      // tile staged
        if (kc < DDIM / KC - 1) {
#pragma unroll
            for (int l0 = 0; l0 < 4; ++l0) {  // prefetch next chunk during compute
                int row = l0 * 32 + pr;
                pa[l0] = x4[(size_t)(tb + row) * 64 + (kc + 1) * 8 + pi];
                pb[l0] = w4[(size_t)(db + row) * 64 + (kc + 1) * 8 + pi];
            }
        }
        tile_fma(sA, sB, tx, ty, acc);
    }

    float bias[8];
#pragma unroll
    for (int c = 0; c < 8; ++c) bias[c] = b[db + tx + 16 * c];
#pragma unroll
    for (int j = 0; j < 8; ++j) {
        size_t rowo = (size_t)(tb + ty + 16 * j) * DDIM + db;
#pragma unroll
        for (int c = 0; c < 8; ++c) {
            float v = acc[j][c] + bias[c];
            int col = tx + 16 * c;
            f[rowo + col] = v;               // fp32 f for exact rescue
            unsigned short h = f2bf(v);
            fhi[rowo + col] = h;
            flo[rowo + col] = f2bf(v - bf2f(h));
        }
    }
}

// ---------------- K3: bf16-split MFMA distances + top-2 argmin ----------------
// d = ||e||^2 - 2*(fhi.ehi + fhi.elo + flo.ehi); exact-fp32 rescue for gap < EPS_GAP.
// 256 thr = 4 waves; 128 tokens/block. B tile (16 codes, hi+lo) staged in LDS with
// 16B-chunk XOR swizzle; next tile's global loads prefetched during MFMA compute.
__global__ __launch_bounds__(256, 2) void k_argmin_mfma(
        const unsigned short* __restrict__ fhi, const unsigned short* __restrict__ flo,
        const unsigned short* __restrict__ ehi, const unsigned short* __restrict__ elo,
        const float* __restrict__ enorm,
        int* __restrict__ idx, int* __restrict__ flaglist, unsigned* __restrict__ flagn) {
    __shared__ bf16x8 sB[1024];       // [hi:0..511][lo:512..1023]; slot = code*32 + (chunk^(code&7))
    const int tid  = threadIdx.x;
    const int lane = tid & 63;
    const int wv   = tid >> 6;
    const int row  = lane & 15;       // A row within tile == D col (code) position
    const int kg   = lane >> 4;       // k-octet group
    const int tok0 = blockIdx.x * 128 + wv * 32;

    // A fragments: 32 tokens x 256 dims (hi+lo) held in registers across whole kernel.
    bf16x8 ah[2][8], al[2][8];
#pragma unroll
    for (int m = 0; m < 2; ++m)
#pragma unroll
        for (int kk = 0; kk < 8; ++kk) {
            size_t off = (size_t)(tok0 + m * 16 + row) * DDIM + kk * 32 + kg * 8;
            ah[m][kk] = *reinterpret_cast<const bf16x8*>(fhi + off);
            al[m][kk] = *reinterpret_cast<const bf16x8*>(flo + off);
        }

    float bd1[2][4], bd2[2][4];
    int   bk1[2][4];
#pragma unroll
    for (int m = 0; m < 2; ++m)
#pragma unroll
        for (int r = 0; r < 4; ++r) { bd1[m][r] = 3.4e38f; bd2[m][r] = 3.4e38f; bk1[m][r] = 0; }

    const int sxr = row & 7;

    bf16x8 st[4];
#pragma unroll
    for (int i = 0; i < 4; ++i) {     // prefetch tile 0
        int c = i * 256 + tid;
        int code = (c >> 5) & 15, ch = c & 31;
        const unsigned short* src = (c < 512) ? ehi : elo;
        st[i] = *reinterpret_cast<const bf16x8*>(src + (size_t)code * DDIM + ch * 8);
    }

#pragma unroll 1
    for (int nt = 0; nt < KCB / 16; ++nt) {
        __syncthreads();   // everyone done reading sB from previous tile
#pragma unroll
        for (int i = 0; i < 4; ++i) {
            int c = i * 256 + tid;
            int code = (c >> 5) & 15, ch = c & 31;
            sB[((c < 512) ? 0 : 512) + code * 32 + (ch ^ (code & 7))] = st[i];
        }
        __syncthreads();   // sB ready
        if (nt < KCB / 16 - 1) {
#pragma unroll
            for (int i = 0; i < 4; ++i) {   // prefetch next tile during MFMA phase
                int c = i * 256 + tid;
                int code = (c >> 5) & 15, ch = c & 31;
                const unsigned short* src = (c < 512) ? ehi : elo;
                st[i] = *reinterpret_cast<const bf16x8*>(
                    src + (size_t)((nt + 1) * 16 + code) * DDIM + ch * 8);
            }
        }

        f32x4 acc0a = {0.f, 0.f, 0.f, 0.f}, acc0b = {0.f, 0.f, 0.f, 0.f};
        f32x4 acc1a = {0.f, 0.f, 0.f, 0.f}, acc1b = {0.f, 0.f, 0.f, 0.f};
#pragma unroll
        for (int kk = 0; kk < 8; ++kk) {
            int slot = row * 32 + (((kk * 4) + kg) ^ sxr);
            bf16x8 bh = sB[slot];
            bf16x8 bl = sB[512 + slot];
            acc0a = __builtin_amdgcn_mfma_f32_16x16x32_bf16(ah[0][kk], bh, acc0a, 0, 0, 0);
            acc1a = __builtin_amdgcn_mfma_f32_16x16x32_bf16(ah[1][kk], bh, acc1a, 0, 0, 0);
            acc0b = __builtin_amdgcn_mfma_f32_16x16x32_bf16(al[0][kk], bh, acc0b, 0, 0, 0);
            acc1b = __builtin_amdgcn_mfma_f32_16x16x32_bf16(al[1][kk], bh, acc1b, 0, 0, 0);
            acc0b = __builtin_amdgcn_mfma_f32_16x16x32_bf16(ah[0][kk], bl, acc0b, 0, 0, 0);
            acc1b = __builtin_amdgcn_mfma_f32_16x16x32_bf16(ah[1][kk], bl, acc1b, 0, 0, 0);
        }

        int code = nt * 16 + row;     // D col = lane&15  [m89-verified layout]
        float en = enorm[code];
#pragma unroll
        for (int r = 0; r < 4; ++r) {
            float d0 = en - 2.f * (acc0a[r] + acc0b[r]);
            float d1 = en - 2.f * (acc1a[r] + acc1b[r]);
            if (d0 < bd1[0][r]) { bd2[0][r] = bd1[0][r]; bd1[0][r] = d0; bk1[0][r] = code; }
            else if (d0 < bd2[0][r]) bd2[0][r] = d0;
            if (d1 < bd1[1][r]) { bd2[1][r] = bd1[1][r]; bd1[1][r] = d1; bk1[1][r] = code; }
            else if (d1 < bd2[1][r]) bd2[1][r] = d1;
        }
    }

    // cross-lane top-2 merge over the 16 code columns (lanes sharing kg group)
#pragma unroll
    for (int m = 0; m < 2; ++m)
#pragma unroll
        for (int r = 0; r < 4; ++r) {
            float v1 = bd1[m][r], v2 = bd2[m][r];
            int k1 = bk1[m][r];
#pragma unroll
            for (int msk = 1; msk < 16; msk <<= 1) {
                float o1 = __shfl_xor(v1, msk, 16);
                float o2 = __shfl_xor(v2, msk, 16);
                int   ok = __shfl_xor(k1, msk, 16);
                if (o1 < v1 || (o1 == v1 && ok < k1)) { v2 = fminf(v1, o2); v1 = o1; k1 = ok; }
                else                                  { v2 = fminf(v2, o1); }
            }
            if (row == 0) {
                int t = tok0 + m * 16 + kg * 4 + r;   // D row = (lane>>4)*4 + reg
                idx[t] = k1;
                if (v2 - v1 < EPS_GAP) {              // too close for bf16 -> exact rescue
                    unsigned p = atomicAdd(flagn, 1u);
                    flaglist[p] = t;
                }
            }
        }
}

// ---------------- K3b: exact fp32 rescue, token-batched + block-parallel ----------------
// 16 tokens per block (f rows in LDS, broadcast reads), thread owns 4 codes with
// dot[4][16] register accumulators. 512 blocks -> all flagged tokens concurrent.
__global__ __launch_bounds__(256) void k_rescore(const float* __restrict__ f,
                                                 const float* __restrict__ emb,
                                                 const float* __restrict__ enorm,
                                                 const int* __restrict__ flaglist,
                                                 const unsigned* __restrict__ flagn,
                                                 int* __restrict__ idx) {
    __shared__ float sf[16 * DDIM];   // 16 f-rows, 16 KB
    __shared__ int   stok[16];
    __shared__ float swd[4 * 16];
    __shared__ int   swk[4 * 16];
    const int tid = threadIdx.x;
    const unsigned n = *flagn;
    const f32x4* f4 = reinterpret_cast<const f32x4*>(f);
    const float4* e4 = reinterpret_cast<const float4*>(emb);
    f32x4* sf4 = reinterpret_cast<f32x4*>(sf);

    float en[4];
#pragma unroll
    for (int c = 0; c < 4; ++c) en[c] = enorm[tid + 256 * c];

#pragma unroll 1
    for (unsigned base = blockIdx.x * 16u; base < n; base += (unsigned)gridDim.x * 16u) {
        const int m = (int)min(16u, n - base);
        __syncthreads();                               // protect sf/stok reuse
        if (tid < 16) stok[tid] = flaglist[base + min(tid, m - 1)];  // pad with first token
        __syncthreads();
#pragma unroll
        for (int i = 0; i < 4; ++i) {                  // stage 16 f-rows (float4-coalesced)
            int t = i * 4 + (tid >> 6), q = tid & 63;
            sf4[t * 64 + q] = f4[(size_t)stok[t] * 64 + q];
        }
        __syncthreads();

        float dot[4][16];
#pragma unroll
        for (int c = 0; c < 4; ++c)
#pragma unroll
            for (int t = 0; t < 16; ++t) dot[c][t] = 0.f;

#pragma unroll 1
        for (int q = 0; q < 64; ++q) {
            float4 ev[4];
#pragma unroll
            for (int c = 0; c < 4; ++c)
                ev[c] = e4[(size_t)(tid + 256 * c) * 64 + q];
#pragma unroll
            for (int t = 0; t < 16; ++t) {
                f32x4 fv = sf4[t * 64 + q];            // wave-uniform broadcast read
#pragma unroll
                for (int c = 0; c < 4; ++c)
                    dot[c][t] += ev[c].x * fv[0] + ev[c].y * fv[1]
                               + ev[c].z * fv[2] + ev[c].w * fv[3];
            }
        }

        // per-token block-wide lexicographic argmin
#pragma unroll 1
        for (int t = 0; t < 16; ++t) {
            float bd = 3.4e38f;
            int   bk = 0x7fffffff;
#pragma unroll
            for (int c = 0; c < 4; ++c) {
                float d = en[c] - 2.f * dot[c][t];
                int   k = tid + 256 * c;
                if (d < bd || (d == bd && k < bk)) { bd = d; bk = k; }
            }
            for (int msk = 1; msk < 64; msk <<= 1) {
                float od = __shfl_xor(bd, msk, 64);
                int   ok = __shfl_xor(bk, msk, 64);
                if (od < bd || (od == bd && ok < bk)) { bd = od; bk = ok; }
            }
            if ((tid & 63) == 0) { swd[(tid >> 6) * 16 + t] = bd; swk[(tid >> 6) * 16 + t] = bk; }
        }
        __syncthreads();
        if (tid < m) {
            float bd = swd[tid]; int bk = swk[tid];
#pragma unroll
            for (int w2 = 1; w2 < 4; ++w2) {
                float od = swd[w2 * 16 + tid]; int ok = swk[w2 * 16 + tid];
                if (od < bd || (od == bd && ok < bk)) { bd = od; bk = ok; }
            }
            idx[stok[tid]] = bk;
        }
    }
}

// ---------------- K4: fused output pass ----------------
// quantized gather + commitment-loss partial + histogram + one-hot encodings rows.
__global__ __launch_bounds__(256) void k_out(const float* __restrict__ x,
                                             const float* __restrict__ emb,
                                             const int* __restrict__ idx,
                                             float* __restrict__ out,
                                             unsigned* __restrict__ counts,
                                             double* __restrict__ lossacc) {
    const int tid = threadIdx.x;
    const int tb = blockIdx.x * 64;  // 64 tokens per block
    __shared__ int   sidx[64];
    __shared__ float wsum[4];
    if (tid < 64) sidx[tid] = idx[tb + tid];
    __syncthreads();

    const float4* x4 = reinterpret_cast<const float4*>(x);
    const float4* e4 = reinterpret_cast<const float4*>(emb);
    float local = 0.f;
#pragma unroll
    for (int it = 0; it < 16; ++it) {
        int l = it * 256 + tid;
        int tok = l >> 6, q = l & 63;   // token-local float4 index
        int t = tb + tok;
        int id = sidx[tok];              // wave-uniform (64 lanes share a token)
        if (q == 0) atomicAdd(&counts[id], 1u);
        float4 xv = x4[(size_t)t * 64 + q];
        float4 ev = e4[(size_t)id * 64 + q];
        size_t o = O_Q + (size_t)t * DDIM + (size_t)q * 4;  // O_Q=1 -> scalar stores
        out[o] = ev.x; out[o + 1] = ev.y; out[o + 2] = ev.z; out[o + 3] = ev.w;
        float dx = ev.x - xv.x, dy = ev.y - xv.y, dz = ev.z - xv.z, dw = ev.w - xv.w;
        local += dx * dx + dy * dy + dz * dz + dw * dw;
    }
    for (int off = 32; off >= 1; off >>= 1) local += __shfl_down(local, off, 64);
    if ((tid & 63) == 0) wsum[tid >> 6] = local;
    __syncthreads();
    if (tid == 0)
        atomicAdd(lossacc, (double)(wsum[0] + wsum[1] + wsum[2] + wsum[3]));

    // one-hot rows: region base is only 8B-aligned (O_E = 2 mod 4 floats) -> float2 stores
#pragma unroll 1
    for (int r = 0; r < 64; ++r) {
        int id = sidx[r];
        float* rb = out + O_E + (size_t)(tb + r) * KCB;
        int hot = id >> 1, sub = id & 1;
#pragma unroll
        for (int i = 0; i < 2; ++i) {
            int q2 = i * 256 + tid;      // float2 index within the 1024-float row
            float2 v = make_float2(0.f, 0.f);
            if (q2 == hot) { if (sub) v.y = 1.f; else v.x = 1.f; }
            *reinterpret_cast<float2*>(rb + (size_t)q2 * 2) = v;
        }
    }
}

// ---------------- K6: loss + perplexity finalize ----------------
__global__ __launch_bounds__(1024) void k_final(const unsigned* __restrict__ counts,
                                                const double* __restrict__ lossacc,
                                                float* __restrict__ out) {
    int tid = threadIdx.x;
    double p = (double)counts[tid] / (double)NTOK;
    double term = p * log(p + 1e-10);
    for (int off = 32; off >= 1; off >>= 1) term += __shfl_down(term, off, 64);
    __shared__ double sw[16];
    if ((tid & 63) == 0) sw[tid >> 6] = term;
    __syncthreads();
    if (tid == 0) {
        double s = 0.0;
        for (int i = 0; i < 16; ++i) s += sw[i];
        out[O_P] = (float)exp(-s);
        out[0]   = (float)(0.25 * lossacc[0] / ((double)NTOK * (double)DDIM));
    }
}

extern "C" void kernel_launch(void* const* d_in, const int* in_sizes, int n_in,
                              void* d_out, int out_size, void* d_ws, size_t ws_size,
                              hipStream_t stream) {
    const float* x   = (const float*)d_in[0];  // [64,2048,256]
    const float* w   = (const float*)d_in[1];  // [256,256]
    const float* b   = (const float*)d_in[2];  // [256]
    const float* emb = (const float*)d_in[3];  // [1024,256]
    float* out = (float*)d_out;

    int*      idx    = (int*)((char*)d_ws + WS_IDX);
    float*    enorm  = (float*)((char*)d_ws + WS_EN);
    unsigned* counts = (unsigned*)((char*)d_ws + WS_CNT);
    double*   acc    = (double*)((char*)d_ws + WS_ACC);
    unsigned* flagn  = (unsigned*)((char*)d_ws + WS_FLAGN);

    float*          scratchF = out + SCRATCH_F_OFF;
    unsigned short* fhi      = (unsigned short*)(out + SCRATCH_FHI);
    unsigned short* flo      = (unsigned short*)(out + SCRATCH_FLO);
    unsigned short* ehi      = (unsigned short*)(out + SCRATCH_EHI);
    unsigned short* elo      = (unsigned short*)(out + SCRATCH_ELO);
    int*            flaglist = (int*)(out + SCRATCH_FLG);

    // zero histogram + loss accumulator + flag count (ws is poisoned each launch)
    hipMemsetAsync((char*)d_ws + WS_CNT, 0, (size_t)KCB * 4 + 16, stream);

    k_enorm      <<<KCB,                        64,  0, stream>>>(emb, enorm, ehi, elo);
    k_gemm1      <<<dim3(NTOK / TS, DDIM / TS), 256, 0, stream>>>(x, w, b, scratchF, fhi, flo);
    k_argmin_mfma<<<NTOK / 128,                 256, 0, stream>>>(fhi, flo, ehi, elo, enorm,
                                                                 idx, flaglist, flagn);
    k_rescore    <<<512,                        256, 0, stream>>>(scratchF, emb, enorm,
                                                                 flaglist, flagn, idx);
    k_out        <<<NTOK / 64,                  256, 0, stream>>>(x, emb, idx, out, counts, acc);
    k_final      <<<1,                          1024, 0, stream>>>(counts, acc, out);
}

// Round 7
// 1438.242 us; speedup vs baseline: 1.2432x; 1.0299x over previous
//
#include <hip/hip_runtime.h>
#include <math.h>

// Problem constants
#define NTOK 131072   // 64 * 2048 tokens
#define DDIM 256      // embedding dim
#define KCB  1024     // codebook size

// Output layout (fp32, concatenated in reference return order)
static constexpr size_t O_Q = 1;                          // quantized_st
static constexpr size_t O_P = 1 + (size_t)NTOK * DDIM;    // perplexity scalar
static constexpr size_t O_E = O_P + 1;                    // encodings [NTOK, KCB]
// scratch lives inside the (not yet written) encodings region.
// O_E = 2^25 + 2 (mod 32 = 2); +30 makes f base 128-B aligned -> full-line stores.
static constexpr size_t SCRATCH_F_OFF = O_E + 30;                                // f fp32 [NTOK][DDIM]
static constexpr size_t SCRATCH_FHI   = SCRATCH_F_OFF + (size_t)NTOK * DDIM;     // f hi bf16 (ushort)
static constexpr size_t SCRATCH_FLO   = SCRATCH_FHI + (size_t)NTOK * DDIM / 2;   // f lo bf16
static constexpr size_t SCRATCH_EHI   = SCRATCH_FLO + (size_t)NTOK * DDIM / 2;   // emb hi bf16
static constexpr size_t SCRATCH_ELO   = SCRATCH_EHI + (size_t)KCB * DDIM / 2;    // emb lo bf16
static constexpr size_t SCRATCH_FLG   = SCRATCH_ELO + (size_t)KCB * DDIM / 2;    // flagged token list (int)
// total scratch ~68M floats < 134M encodings floats; all dead before k_out overwrites.

// ws layout (bytes)
static constexpr size_t WS_IDX   = 0;                         // NTOK * int
static constexpr size_t WS_EN    = (size_t)NTOK * 4;          // KCB * float (||e||^2)
static constexpr size_t WS_CNT   = WS_EN + (size_t)KCB * 4;   // KCB * uint (histogram)
static constexpr size_t WS_ACC   = WS_CNT + (size_t)KCB * 4;  // double (loss accumulator)
static constexpr size_t WS_FLAGN = WS_ACC + 8;                // uint (flagged-token count)

#define TS 128     // block tile (tokens) for fp32 gemm1
#define KC 32      // reduction chunk staged in LDS (gemm1)
#define LDSROW 36  // padded row stride (gemm1)

#define EPS_GAP 0.0625f   // >=30x worst-case bf16-split dot error; flags ~3% of tokens

typedef short bf16x8 __attribute__((ext_vector_type(8)));
typedef float f32x4  __attribute__((ext_vector_type(4)));
typedef unsigned short us4v __attribute__((ext_vector_type(4)));
typedef unsigned short us8v __attribute__((ext_vector_type(8)));

__device__ __forceinline__ unsigned short f2bf(float x) {   // RNE float->bf16
    unsigned u = __float_as_uint(x);
    return (unsigned short)((u + 0x7FFFu + ((u >> 16) & 1u)) >> 16);
}
__device__ __forceinline__ float bf2f(unsigned short h) {
    return __uint_as_float(((unsigned)h) << 16);
}

// ---------------- K1: codebook squared norms + bf16 hi/lo split ----------------
__global__ __launch_bounds__(64) void k_enorm(const float* __restrict__ emb,
                                              float* __restrict__ enorm,
                                              unsigned short* __restrict__ ehi,
                                              unsigned short* __restrict__ elo) {
    int k = blockIdx.x;
    float4 v = reinterpret_cast<const float4*>(emb)[(size_t)k * 64 + threadIdx.x];
    float s = v.x * v.x + v.y * v.y + v.z * v.z + v.w * v.w;

    float xs[4] = {v.x, v.y, v.z, v.w};
    us4v hv, lv;
#pragma unroll
    for (int i = 0; i < 4; ++i) {
        unsigned short h = f2bf(xs[i]);
        hv[i] = h;
        lv[i] = f2bf(xs[i] - bf2f(h));
    }
    *reinterpret_cast<us4v*>(ehi + (size_t)k * DDIM + threadIdx.x * 4) = hv;
    *reinterpret_cast<us4v*>(elo + (size_t)k * DDIM + threadIdx.x * 4) = lv;

    for (int off = 32; off >= 1; off >>= 1) s += __shfl_down(s, off, 64);
    if (threadIdx.x == 0) enorm[k] = s;
}

// fp32 inner-product micro-kernel (gemm1). acc/bv register-promoted; is-loop
// rolled on purpose (full unroll demotes arrays to scratch).
__device__ __forceinline__ void tile_fma(const float* __restrict__ sA,
                                         const float* __restrict__ sB,
                                         int tx, int ty,
                                         float acc[8][8]) {
#pragma unroll 1
    for (int is = 0; is < 8; ++is) {
        float4 bv[8];
#pragma unroll
        for (int c = 0; c < 8; ++c)
            bv[c] = *reinterpret_cast<const float4*>(&sB[(tx + 16 * c) * LDSROW + is * 4]);
#pragma unroll
        for (int j = 0; j < 8; ++j) {
            float4 a = *reinterpret_cast<const float4*>(&sA[(ty + 16 * j) * LDSROW + is * 4]);
#pragma unroll
            for (int c = 0; c < 8; ++c)
                acc[j][c] += a.x * bv[c].x + a.y * bv[c].y + a.z * bv[c].z + a.w * bv[c].w;
        }
    }
}

// ---------------- K2: f = x @ W^T + b  (fp32) -> f fp32 + bf16 hi/lo ----------------
// Register-prefetch pipeline + LDS-transposed epilogue (full-line coalesced stores:
// round-4 PMC showed 3x WRITE_SIZE amplification from 64B/32B partial-line stores).
__global__ __launch_bounds__(256, 2) void k_gemm1(const float* __restrict__ x,
                                                  const float* __restrict__ w,
                                                  const float* __restrict__ b,
                                                  float* __restrict__ f,
                                                  unsigned short* __restrict__ fhi,
                                                  unsigned short* __restrict__ flo) {
    __shared__ float sA[TS * LDSROW];
    __shared__ float sB[TS * LDSROW];
    const int tid = threadIdx.x;
    const int tx = tid & 15, ty = tid >> 4;
    const int tb = blockIdx.x * TS;   // token base
    const int db = blockIdx.y * TS;   // output-dim base

    float acc[8][8];
#pragma unroll
    for (int j = 0; j < 8; ++j)
#pragma unroll
        for (int c = 0; c < 8; ++c) acc[j][c] = 0.f;

    const float4* x4 = reinterpret_cast<const float4*>(x);
    const float4* w4 = reinterpret_cast<const float4*>(w);

    const int pr = tid >> 3, pi = tid & 7;   // 1024 float4 per tile: 4 chunks/thread
    float4 pa[4], pb[4];
#pragma unroll
    for (int l0 = 0; l0 < 4; ++l0) {
        int row = l0 * 32 + pr;
        pa[l0] = x4[(size_t)(tb + row) * 64 + pi];
        pb[l0] = w4[(size_t)(db + row) * 64 + pi];
    }

#pragma unroll 1
    for (int kc = 0; kc < DDIM / KC; ++kc) {
        __syncthreads();                      // readers of previous tile done
#pragma unroll
        for (int l0 = 0; l0 < 4; ++l0) {
            int row = l0 * 32 + pr;
            *reinterpret_cast<float4*>(&sA[row * LDSROW + pi * 4]) = pa[l0];
            *reinterpret_cast<float4*>(&sB[row * LDSROW + pi * 4]) = pb[l0];
        }
        __syncthreads();                      // tile staged
        if (kc < DDIM / KC - 1) {
#pragma unroll
            for (int l0 = 0; l0 < 4; ++l0) {  // prefetch next chunk during compute
                int row = l0 * 32 + pr;
                pa[l0] = x4[(size_t)(tb + row) * 64 + (kc + 1) * 8 + pi];
                pb[l0] = w4[(size_t)(db + row) * 64 + (kc + 1) * 8 + pi];
            }
        }
        tile_fma(sA, sB, tx, ty, acc);
    }

    float bias[8];
#pragma unroll
    for (int c = 0; c < 8; ++c) bias[c] = b[db + tx + 16 * c];

    // LDS-transposed epilogue: 4 fully-unrolled passes of 32 rows x 128 cols staged
    // in sA (32 x 132-pad = 16.9 KB <= sA). acc stays compile-time-indexed (rule #20).
#pragma unroll
    for (int p = 0; p < 4; ++p) {
        __syncthreads();                      // sA readers (tile_fma / prev pass) done
#pragma unroll
        for (int jj = 0; jj < 2; ++jj) {
            int lr = ty + 16 * jj;            // local row 0..31  (global row ty+16*(2p+jj))
#pragma unroll
            for (int c = 0; c < 8; ++c)
                sA[lr * 132 + tx + 16 * c] = acc[2 * p + jj][c] + bias[c];
        }
        __syncthreads();
        // f fp32: thread owns (row=tid>>3, 4xfloat4 at cols (tid&7)*4 + 32i)
        // -> per instruction 8 lanes cover 128 contiguous, line-aligned bytes.
        {
            int row = tid >> 3, seg = tid & 7;
            size_t go = (size_t)(tb + 32 * p + row) * DDIM + db;
#pragma unroll
            for (int i = 0; i < 4; ++i) {
                int col = seg * 4 + 32 * i;
                *reinterpret_cast<f32x4*>(&f[go + col]) =
                    *reinterpret_cast<const f32x4*>(&sA[row * 132 + col]);
            }
        }
        // fhi/flo: thread owns 8 consecutive ushorts; 16 lanes = 256 B (2 full lines).
#pragma unroll
        for (int it = 0; it < 2; ++it) {
            int a2 = it * 256 + tid;
            int row = a2 >> 4, seg = a2 & 15;
            size_t go = (size_t)(tb + 32 * p + row) * DDIM + db + seg * 8;
            us8v hv, lv;
#pragma unroll
            for (int k2 = 0; k2 < 8; ++k2) {
                float v = sA[row * 132 + seg * 8 + k2];
                unsigned short h = f2bf(v);
                hv[k2] = h;
                lv[k2] = f2bf(v - bf2f(h));
            }
            *reinterpret_cast<us8v*>(fhi + go) = hv;
            *reinterpret_cast<us8v*>(flo + go) = lv;
        }
    }
}

// ---------------- K3: bf16-split MFMA distances + top-2 argmin ----------------
// d = ||e||^2 - 2*(fhi.ehi + fhi.elo + flo.ehi); exact-fp32 rescue for gap < EPS_GAP.
// 256 thr = 4 waves; 128 tokens/block. B tile (16 codes, hi+lo) staged in LDS with
// 16B-chunk XOR swizzle; next tile's global loads prefetched during MFMA compute.
__global__ __launch_bounds__(256, 2) void k_argmin_mfma(
        const unsigned short* __restrict__ fhi, const unsigned short* __restrict__ flo,
        const unsigned short* __restrict__ ehi, const unsigned short* __restrict__ elo,
        const float* __restrict__ enorm,
        int* __restrict__ idx, int* __restrict__ flaglist, unsigned* __restrict__ flagn) {
    __shared__ bf16x8 sB[1024];       // [hi:0..511][lo:512..1023]; slot = code*32 + (chunk^(code&7))
    const int tid  = threadIdx.x;
    const int lane = tid & 63;
    const int wv   = tid >> 6;
    const int row  = lane & 15;       // A row within tile == D col (code) position
    const int kg   = lane >> 4;       // k-octet group
    const int tok0 = blockIdx.x * 128 + wv * 32;

    // A fragments: 32 tokens x 256 dims (hi+lo) held in registers across whole kernel.
    bf16x8 ah[2][8], al[2][8];
#pragma unroll
    for (int m = 0; m < 2; ++m)
#pragma unroll
        for (int kk = 0; kk < 8; ++kk) {
            size_t off = (size_t)(tok0 + m * 16 + row) * DDIM + kk * 32 + kg * 8;
            ah[m][kk] = *reinterpret_cast<const bf16x8*>(fhi + off);
            al[m][kk] = *reinterpret_cast<const bf16x8*>(flo + off);
        }

    float bd1[2][4], bd2[2][4];
    int   bk1[2][4];
#pragma unroll
    for (int m = 0; m < 2; ++m)
#pragma unroll
        for (int r = 0; r < 4; ++r) { bd1[m][r] = 3.4e38f; bd2[m][r] = 3.4e38f; bk1[m][r] = 0; }

    const int sxr = row & 7;

    bf16x8 st[4];
#pragma unroll
    for (int i = 0; i < 4; ++i) {     // prefetch tile 0
        int c = i * 256 + tid;
        int code = (c >> 5) & 15, ch = c & 31;
        const unsigned short* src = (c < 512) ? ehi : elo;
        st[i] = *reinterpret_cast<const bf16x8*>(src + (size_t)code * DDIM + ch * 8);
    }

#pragma unroll 1
    for (int nt = 0; nt < KCB / 16; ++nt) {
        __syncthreads();   // everyone done reading sB from previous tile
#pragma unroll
        for (int i = 0; i < 4; ++i) {
            int c = i * 256 + tid;
            int code = (c >> 5) & 15, ch = c & 31;
            sB[((c < 512) ? 0 : 512) + code * 32 + (ch ^ (code & 7))] = st[i];
        }
        __syncthreads();   // sB ready
        if (nt < KCB / 16 - 1) {
#pragma unroll
            for (int i = 0; i < 4; ++i) {   // prefetch next tile during MFMA phase
                int c = i * 256 + tid;
                int code = (c >> 5) & 15, ch = c & 31;
                const unsigned short* src = (c < 512) ? ehi : elo;
                st[i] = *reinterpret_cast<const bf16x8*>(
                    src + (size_t)((nt + 1) * 16 + code) * DDIM + ch * 8);
            }
        }

        f32x4 acc0a = {0.f, 0.f, 0.f, 0.f}, acc0b = {0.f, 0.f, 0.f, 0.f};
        f32x4 acc1a = {0.f, 0.f, 0.f, 0.f}, acc1b = {0.f, 0.f, 0.f, 0.f};
#pragma unroll
        for (int kk = 0; kk < 8; ++kk) {
            int slot = row * 32 + (((kk * 4) + kg) ^ sxr);
            bf16x8 bh = sB[slot];
            bf16x8 bl = sB[512 + slot];
            acc0a = __builtin_amdgcn_mfma_f32_16x16x32_bf16(ah[0][kk], bh, acc0a, 0, 0, 0);
            acc1a = __builtin_amdgcn_mfma_f32_16x16x32_bf16(ah[1][kk], bh, acc1a, 0, 0, 0);
            acc0b = __builtin_amdgcn_mfma_f32_16x16x32_bf16(al[0][kk], bh, acc0b, 0, 0, 0);
            acc1b = __builtin_amdgcn_mfma_f32_16x16x32_bf16(al[1][kk], bh, acc1b, 0, 0, 0);
            acc0b = __builtin_amdgcn_mfma_f32_16x16x32_bf16(ah[0][kk], bl, acc0b, 0, 0, 0);
            acc1b = __builtin_amdgcn_mfma_f32_16x16x32_bf16(ah[1][kk], bl, acc1b, 0, 0, 0);
        }

        int code = nt * 16 + row;     // D col = lane&15  [m89-verified layout]
        float en = enorm[code];
#pragma unroll
        for (int r = 0; r < 4; ++r) {
            float d0 = en - 2.f * (acc0a[r] + acc0b[r]);
            float d1 = en - 2.f * (acc1a[r] + acc1b[r]);
            if (d0 < bd1[0][r]) { bd2[0][r] = bd1[0][r]; bd1[0][r] = d0; bk1[0][r] = code; }
            else if (d0 < bd2[0][r]) bd2[0][r] = d0;
            if (d1 < bd1[1][r]) { bd2[1][r] = bd1[1][r]; bd1[1][r] = d1; bk1[1][r] = code; }
            else if (d1 < bd2[1][r]) bd2[1][r] = d1;
        }
    }

    // cross-lane top-2 merge over the 16 code columns (lanes sharing kg group)
#pragma unroll
    for (int m = 0; m < 2; ++m)
#pragma unroll
        for (int r = 0; r < 4; ++r) {
            float v1 = bd1[m][r], v2 = bd2[m][r];
            int k1 = bk1[m][r];
#pragma unroll
            for (int msk = 1; msk < 16; msk <<= 1) {
                float o1 = __shfl_xor(v1, msk, 16);
                float o2 = __shfl_xor(v2, msk, 16);
                int   ok = __shfl_xor(k1, msk, 16);
                if (o1 < v1 || (o1 == v1 && ok < k1)) { v2 = fminf(v1, o2); v1 = o1; k1 = ok; }
                else                                  { v2 = fminf(v2, o1); }
            }
            if (row == 0) {
                int t = tok0 + m * 16 + kg * 4 + r;   // D row = (lane>>4)*4 + reg
                idx[t] = k1;
                if (v2 - v1 < EPS_GAP) {              // too close for bf16 -> exact rescue
                    unsigned p = atomicAdd(flagn, 1u);
                    flaglist[p] = t;
                }
            }
        }
}

// ---------------- K3b: exact fp32 rescue, token-batched + block-parallel ----------------
// 16 tokens per block (f rows in LDS, broadcast reads), thread owns 4 codes with
// dot[4][16] register accumulators. 512 blocks -> all flagged tokens concurrent.
__global__ __launch_bounds__(256) void k_rescore(const float* __restrict__ f,
                                                 const float* __restrict__ emb,
                                                 const float* __restrict__ enorm,
                                                 const int* __restrict__ flaglist,
                                                 const unsigned* __restrict__ flagn,
                                                 int* __restrict__ idx) {
    __shared__ float sf[16 * DDIM];   // 16 f-rows, 16 KB
    __shared__ int   stok[16];
    __shared__ float swd[4 * 16];
    __shared__ int   swk[4 * 16];
    const int tid = threadIdx.x;
    const unsigned n = *flagn;
    const f32x4* f4 = reinterpret_cast<const f32x4*>(f);
    const float4* e4 = reinterpret_cast<const float4*>(emb);
    f32x4* sf4 = reinterpret_cast<f32x4*>(sf);

    float en[4];
#pragma unroll
    for (int c = 0; c < 4; ++c) en[c] = enorm[tid + 256 * c];

#pragma unroll 1
    for (unsigned base = blockIdx.x * 16u; base < n; base += (unsigned)gridDim.x * 16u) {
        const int m = (int)min(16u, n - base);
        __syncthreads();                               // protect sf/stok reuse
        if (tid < 16) stok[tid] = flaglist[base + min(tid, m - 1)];  // pad with first token
        __syncthreads();
#pragma unroll
        for (int i = 0; i < 4; ++i) {                  // stage 16 f-rows (float4-coalesced)
            int t = i * 4 + (tid >> 6), q = tid & 63;
            sf4[t * 64 + q] = f4[(size_t)stok[t] * 64 + q];
        }
        __syncthreads();

        float dot[4][16];
#pragma unroll
        for (int c = 0; c < 4; ++c)
#pragma unroll
            for (int t = 0; t < 16; ++t) dot[c][t] = 0.f;

#pragma unroll 1
        for (int q = 0; q < 64; ++q) {
            float4 ev[4];
#pragma unroll
            for (int c = 0; c < 4; ++c)
                ev[c] = e4[(size_t)(tid + 256 * c) * 64 + q];
#pragma unroll
            for (int t = 0; t < 16; ++t) {
                f32x4 fv = sf4[t * 64 + q];            // wave-uniform broadcast read
#pragma unroll
                for (int c = 0; c < 4; ++c)
                    dot[c][t] += ev[c].x * fv[0] + ev[c].y * fv[1]
                               + ev[c].z * fv[2] + ev[c].w * fv[3];
            }
        }

        // per-token block-wide lexicographic argmin
#pragma unroll 1
        for (int t = 0; t < 16; ++t) {
            float bd = 3.4e38f;
            int   bk = 0x7fffffff;
#pragma unroll
            for (int c = 0; c < 4; ++c) {
                float d = en[c] - 2.f * dot[c][t];
                int   k = tid + 256 * c;
                if (d < bd || (d == bd && k < bk)) { bd = d; bk = k; }
            }
            for (int msk = 1; msk < 64; msk <<= 1) {
                float od = __shfl_xor(bd, msk, 64);
                int   ok = __shfl_xor(bk, msk, 64);
                if (od < bd || (od == bd && ok < bk)) { bd = od; bk = ok; }
            }
            if ((tid & 63) == 0) { swd[(tid >> 6) * 16 + t] = bd; swk[(tid >> 6) * 16 + t] = bk; }
        }
        __syncthreads();
        if (tid < m) {
            float bd = swd[tid]; int bk = swk[tid];
#pragma unroll
            for (int w2 = 1; w2 < 4; ++w2) {
                float od = swd[w2 * 16 + tid]; int ok = swk[w2 * 16 + tid];
                if (od < bd || (od == bd && ok < bk)) { bd = od; bk = ok; }
            }
            idx[stok[tid]] = bk;
        }
    }
}

// ---------------- K4: fused output pass ----------------
// quantized gather + commitment-loss partial + histogram + one-hot encodings rows.
__global__ __launch_bounds__(256) void k_out(const float* __restrict__ x,
                                             const float* __restrict__ emb,
                                             const int* __restrict__ idx,
                                             float* __restrict__ out,
                                             unsigned* __restrict__ counts,
                                             double* __restrict__ lossacc) {
    const int tid = threadIdx.x;
    const int tb = blockIdx.x * 64;  // 64 tokens per block
    __shared__ int   sidx[64];
    __shared__ float wsum[4];
    if (tid < 64) sidx[tid] = idx[tb + tid];
    __syncthreads();

    const float4* x4 = reinterpret_cast<const float4*>(x);
    const float4* e4 = reinterpret_cast<const float4*>(emb);
    float local = 0.f;
#pragma unroll
    for (int it = 0; it < 16; ++it) {
        int l = it * 256 + tid;
        int tok = l >> 6, q = l & 63;   // token-local float4 index
        int t = tb + tok;
        int id = sidx[tok];              // wave-uniform (64 lanes share a token)
        if (q == 0) atomicAdd(&counts[id], 1u);
        float4 xv = x4[(size_t)t * 64 + q];
        float4 ev = e4[(size_t)id * 64 + q];
        size_t o = O_Q + (size_t)t * DDIM + (size_t)q * 4;  // O_Q=1 -> scalar stores
        out[o] = ev.x; out[o + 1] = ev.y; out[o + 2] = ev.z; out[o + 3] = ev.w;
        float dx = ev.x - xv.x, dy = ev.y - xv.y, dz = ev.z - xv.z, dw = ev.w - xv.w;
        local += dx * dx + dy * dy + dz * dz + dw * dw;
    }
    for (int off = 32; off >= 1; off >>= 1) local += __shfl_down(local, off, 64);
    if ((tid & 63) == 0) wsum[tid >> 6] = local;
    __syncthreads();
    if (tid == 0)
        atomicAdd(lossacc, (double)(wsum[0] + wsum[1] + wsum[2] + wsum[3]));

    // one-hot rows: region base is only 8B-aligned (O_E = 2 mod 4 floats) -> float2 stores
#pragma unroll 1
    for (int r = 0; r < 64; ++r) {
        int id = sidx[r];
        float* rb = out + O_E + (size_t)(tb + r) * KCB;
        int hot = id >> 1, sub = id & 1;
#pragma unroll
        for (int i = 0; i < 2; ++i) {
            int q2 = i * 256 + tid;      // float2 index within the 1024-float row
            float2 v = make_float2(0.f, 0.f);
            if (q2 == hot) { if (sub) v.y = 1.f; else v.x = 1.f; }
            *reinterpret_cast<float2*>(rb + (size_t)q2 * 2) = v;
        }
    }
}

// ---------------- K6: loss + perplexity finalize ----------------
__global__ __launch_bounds__(1024) void k_final(const unsigned* __restrict__ counts,
                                                const double* __restrict__ lossacc,
                                                float* __restrict__ out) {
    int tid = threadIdx.x;
    double p = (double)counts[tid] / (double)NTOK;
    double term = p * log(p + 1e-10);
    for (int off = 32; off >= 1; off >>= 1) term += __shfl_down(term, off, 64);
    __shared__ double sw[16];
    if ((tid & 63) == 0) sw[tid >> 6] = term;
    __syncthreads();
    if (tid == 0) {
        double s = 0.0;
        for (int i = 0; i < 16; ++i) s += sw[i];
        out[O_P] = (float)exp(-s);
        out[0]   = (float)(0.25 * lossacc[0] / ((double)NTOK * (double)DDIM));
    }
}

extern "C" void kernel_launch(void* const* d_in, const int* in_sizes, int n_in,
                              void* d_out, int out_size, void* d_ws, size_t ws_size,
                              hipStream_t stream) {
    const float* x   = (const float*)d_in[0];  // [64,2048,256]
    const float* w   = (const float*)d_in[1];  // [256,256]
    const float* b   = (const float*)d_in[2];  // [256]
    const float* emb = (const float*)d_in[3];  // [1024,256]
    float* out = (float*)d_out;

    int*      idx    = (int*)((char*)d_ws + WS_IDX);
    float*    enorm  = (float*)((char*)d_ws + WS_EN);
    unsigned* counts = (unsigned*)((char*)d_ws + WS_CNT);
    double*   acc    = (double*)((char*)d_ws + WS_ACC);
    unsigned* flagn  = (unsigned*)((char*)d_ws + WS_FLAGN);

    float*          scratchF = out + SCRATCH_F_OFF;
    unsigned short* fhi      = (unsigned short*)(out + SCRATCH_FHI);
    unsigned short* flo      = (unsigned short*)(out + SCRATCH_FLO);
    unsigned short* ehi      = (unsigned short*)(out + SCRATCH_EHI);
    unsigned short* elo      = (unsigned short*)(out + SCRATCH_ELO);
    int*            flaglist = (int*)(out + SCRATCH_FLG);

    // zero histogram + loss accumulator + flag count (ws is poisoned each launch)
    hipMemsetAsync((char*)d_ws + WS_CNT, 0, (size_t)KCB * 4 + 16, stream);

    k_enorm      <<<KCB,                        64,  0, stream>>>(emb, enorm, ehi, elo);
    k_gemm1      <<<dim3(NTOK / TS, DDIM / TS), 256, 0, stream>>>(x, w, b, scratchF, fhi, flo);
    k_argmin_mfma<<<NTOK / 128,                 256, 0, stream>>>(fhi, flo, ehi, elo, enorm,
                                                                 idx, flaglist, flagn);
    k_rescore    <<<512,                        256, 0, stream>>>(scratchF, emb, enorm,
                                                                 flaglist, flagn, idx);
    k_out        <<<NTOK / 64,                  256, 0, stream>>>(x, emb, idx, out, counts, acc);
    k_final      <<<1,                          1024, 0, stream>>>(counts, acc, out);
}